// Round 1
// baseline (288.708 us; speedup 1.0000x reference)
//
#include <hip/hip_runtime.h>
#include <math.h>

#define D_MODEL 1024
#define D_INT   64
#define KW      32
#define L_SEQ   4096
#define SUBHEADS 5
#define HEADS   14
#define M_ROWS  8192
#define N_CAT   896
#define NQK     320          // SUBHEADS*64

typedef unsigned short us;
typedef unsigned int   uu;
typedef __attribute__((ext_vector_type(4))) unsigned int uu4;
typedef __attribute__((ext_vector_type(8))) short bf16x8_t;
typedef __attribute__((ext_vector_type(4))) float f32x4_t;

__device__ __forceinline__ float u2f(uu u) {
    float f; __builtin_memcpy(&f, &u, 4); return f;
}
__device__ __forceinline__ float blo(uu u) { return u2f(u << 16); }
__device__ __forceinline__ float bhi(uu u) { return u2f(u & 0xffff0000u); }
__device__ __forceinline__ us f2b(float f) {
    uu u; __builtin_memcpy(&u, &f, 4);
    u += 0x7fffu + ((u >> 16) & 1u);
    return (us)(u >> 16);
}
__device__ __forceinline__ uu pack2(float a, float b) {
    return (uu)f2b(a) | ((uu)f2b(b) << 16);
}
// hardware packed cvt: dst = {bf16(a) lo, bf16(b) hi}, RNE — bit-identical to pack2
__device__ __forceinline__ uu cvtpk(float a, float b) {
    uu r;
    asm("v_cvt_pk_bf16_f32 %0, %1, %2" : "=v"(r) : "v"(a), "v"(b));
    return r;
}
__device__ __forceinline__ void load16(void* lds, const void* g) {
    __builtin_amdgcn_global_load_lds(
        (const __attribute__((address_space(1))) unsigned int*)g,
        (__attribute__((address_space(3))) unsigned int*)lds, 16, 0, 0);
}
__device__ __forceinline__ int subhead_of(int h) {
    return (h < 5) ? 0 : (h < 10) ? 1 : (h < 12) ? 2 : (h == 12) ? 3 : 4;
}
__device__ __forceinline__ int dil_of_sub(int s) {
    return (s <= 1) ? 1 : (1 << (s - 1));   // 1,1,2,4,8
}

// ---------------------------------------------------------------------------
// Prep: weight transpose-casts only (Wq,Wk,Wv,Wc). q/k/v casts are fused into
// the projection GEMMs (fp32 A reg-staging), killing the 150 MB round-trip.
// grid: 320+320+896+896 = 2432 blocks
// ---------------------------------------------------------------------------
__global__ __launch_bounds__(256)
void prep_kernel(const float* __restrict__ Wq, const float* __restrict__ Wk,
                 const float* __restrict__ Wv, const float* __restrict__ Wc,
                 us* __restrict__ Wqt, us* __restrict__ Wkt,
                 us* __restrict__ Wvt, us* __restrict__ Wct)
{
    __shared__ float t[32][33];
    const int tid = threadIdx.x;
    int g = blockIdx.x;
    const float* S; us* D; int K, N;
    if (g < 640) {
        if (g < 320) { S = Wq; D = Wqt; } else { S = Wk; D = Wkt; g -= 320; }
        K = 1024; N = 64;
    } else if (g < 1536) {
        g -= 640; S = Wv; D = Wvt; K = 1024; N = 64;
    } else {
        g -= 1536; S = Wc; D = Wct; K = 896; N = 1024;
    }
    const int nkx = K >> 5;
    const int kx = g % nkx;
    const int rest = g / nkx;
    const int ny = rest % (N >> 5);
    const int z  = rest / (N >> 5);
    const int k0 = kx * 32, n0 = ny * 32;
    S += (size_t)z * K * N;
    D += (size_t)z * K * N;
    const int tx = tid & 31, ty = tid >> 5;
#pragma unroll
    for (int r = 0; r < 32; r += 8)
        t[r + ty][tx] = S[(size_t)(k0 + r + ty) * N + n0 + tx];
    __syncthreads();
#pragma unroll
    for (int r = 0; r < 32; r += 8)
        D[(size_t)(n0 + r + ty) * K + k0 + tx] = f2b(t[tx][r + ty]);
}

// ---------------------------------------------------------------------------
// shared 128x64-tile GEMM core (BK=64, XOR-swizzled LDS).
// AF32: A is fp32 in global; reg-stage (2x dwordx4 -> cvt_pk -> ds_write_b128)
// to the SAME swizzled LDS layout the gload_lds path produces:
//   LDS row (w*32+p*8+sr), slot (lane&7)  <=  global col slot scs=(lane&7)^sr
// ---------------------------------------------------------------------------
template<bool AF32>
__device__ __forceinline__
void gemm64_core(const void* __restrict__ Av, const us* __restrict__ Bt,
                 const float* __restrict__ bias, us* __restrict__ C,
                 int K, int ldC, int row0, int col0, us* As, us* Bs)
{
    const int tid = threadIdx.x, w = tid >> 6, lane = tid & 63;
    const int m = lane & 15, quad = lane >> 4;
    const int sr = lane >> 3;
    const int scs = (lane & 7) ^ sr;

    f32x4_t z4 = {0.f, 0.f, 0.f, 0.f};
    f32x4_t acc[2][4] = {{z4, z4, z4, z4}, {z4, z4, z4, z4}};

    for (int k0 = 0; k0 < K; k0 += 64) {
#pragma unroll
        for (int p = 0; p < 2; p++) {
            const int r = w * 16 + p * 8 + sr;
            load16(&Bs[(w * 16 + p * 8) * 64], Bt + (size_t)(col0 + r) * K + k0 + scs * 8);
        }
#pragma unroll
        for (int p = 0; p < 4; p++) {
            const int r = w * 32 + p * 8 + sr;
            if constexpr (AF32) {
                const float* ag = (const float*)Av + (size_t)(row0 + r) * K + k0 + scs * 8;
                float4 x0 = *(const float4*)ag;
                float4 x1 = *(const float4*)(ag + 4);
                uu4 o;
                o.x = cvtpk(x0.x, x0.y); o.y = cvtpk(x0.z, x0.w);
                o.z = cvtpk(x1.x, x1.y); o.w = cvtpk(x1.z, x1.w);
                *(uu4*)&As[(w * 32 + p * 8 + sr) * 64 + (lane & 7) * 8] = o;
            } else {
                load16(&As[(w * 32 + p * 8) * 64],
                       (const us*)Av + (size_t)(row0 + r) * K + k0 + scs * 8);
            }
        }
        __syncthreads();
#pragma unroll
        for (int ks = 0; ks < 2; ks++) {
            const int slot = ((ks * 4 + quad) ^ (m & 7)) * 8;
            bf16x8_t a0 = *(const bf16x8_t*)&As[(w * 32 + m) * 64 + slot];
            bf16x8_t a1 = *(const bf16x8_t*)&As[(w * 32 + 16 + m) * 64 + slot];
#pragma unroll
            for (int t = 0; t < 4; t++) {
                bf16x8_t bb = *(const bf16x8_t*)&Bs[(t * 16 + m) * 64 + slot];
                acc[0][t] = __builtin_amdgcn_mfma_f32_16x16x32_bf16(a0, bb, acc[0][t], 0, 0, 0);
                acc[1][t] = __builtin_amdgcn_mfma_f32_16x16x32_bf16(a1, bb, acc[1][t], 0, 0, 0);
            }
        }
        __syncthreads();
    }

#pragma unroll
    for (int tm = 0; tm < 2; tm++) {
        const int rbase = row0 + w * 32 + tm * 16 + quad * 4;
#pragma unroll
        for (int t = 0; t < 4; t++) {
            const int col = col0 + t * 16 + m;
            const float bi = bias[col];
#pragma unroll
            for (int r = 0; r < 4; r++)
                C[(size_t)(rbase + r) * ldC + col] = f2b(acc[tm][t][r] + bi);
        }
    }
}

// ---------------------------------------------------------------------------
// 128x128-tile core (m97 structure), same AF32 reg-staging option.
// ---------------------------------------------------------------------------
template<bool AF32>
__device__ __forceinline__
void gemm128_core(const void* __restrict__ Av, const us* __restrict__ Bt,
                  const float* __restrict__ bias, void* __restrict__ Cv,
                  int K, int ldC, int outBf16, int row0, int col0,
                  us* As, us* Bs)
{
    const int tid = threadIdx.x, w = tid >> 6, lane = tid & 63;
    const int m = lane & 15, quad = lane >> 4;
    const int sr = lane >> 3;
    const int scs = (lane & 7) ^ sr;
    const int mrow0 = (w & 1) * 64, ncol0 = (w >> 1) * 64;

    f32x4_t z = {0.f, 0.f, 0.f, 0.f};
    f32x4_t acc[4][4] = {{z,z,z,z},{z,z,z,z},{z,z,z,z},{z,z,z,z}};

    for (int k0 = 0; k0 < K; k0 += 64) {
#pragma unroll
        for (int p = 0; p < 4; p++) {
            const int r = w * 32 + p * 8 + sr;
            load16(&Bs[(w * 32 + p * 8) * 64], Bt + (size_t)(col0 + r) * K + k0 + scs * 8);
            if constexpr (AF32) {
                const float* ag = (const float*)Av + (size_t)(row0 + r) * K + k0 + scs * 8;
                float4 x0 = *(const float4*)ag;
                float4 x1 = *(const float4*)(ag + 4);
                uu4 o;
                o.x = cvtpk(x0.x, x0.y); o.y = cvtpk(x0.z, x0.w);
                o.z = cvtpk(x1.x, x1.y); o.w = cvtpk(x1.z, x1.w);
                *(uu4*)&As[(w * 32 + p * 8 + sr) * 64 + (lane & 7) * 8] = o;
            } else {
                load16(&As[(w * 32 + p * 8) * 64],
                       (const us*)Av + (size_t)(row0 + r) * K + k0 + scs * 8);
            }
        }
        __syncthreads();
#pragma unroll
        for (int ks = 0; ks < 2; ks++) {
            const int slot = ((ks * 4 + quad) ^ (m & 7)) * 8;
            bf16x8_t a[4], b[4];
#pragma unroll
            for (int t = 0; t < 4; t++) {
                a[t] = *(const bf16x8_t*)&As[(mrow0 + t * 16 + m) * 64 + slot];
                b[t] = *(const bf16x8_t*)&Bs[(ncol0 + t * 16 + m) * 64 + slot];
            }
#pragma unroll
            for (int i = 0; i < 4; i++)
#pragma unroll
                for (int j = 0; j < 4; j++)
                    acc[i][j] = __builtin_amdgcn_mfma_f32_16x16x32_bf16(a[i], b[j], acc[i][j], 0, 0, 0);
        }
        __syncthreads();
    }

#pragma unroll
    for (int i = 0; i < 4; i++) {
        const int rbase = row0 + mrow0 + i * 16 + quad * 4;
        if (outBf16) {
            us* Cb = (us*)Cv;
#pragma unroll
            for (int j = 0; j < 4; j++) {
                const int col = col0 + ncol0 + j * 16 + m;
                const float bi = bias[col];
#pragma unroll
                for (int r = 0; r < 4; r++)
                    Cb[(size_t)(rbase + r) * ldC + col] = f2b(acc[i][j][r] + bi);
            }
        } else {
            float* Cb = (float*)Cv;
#pragma unroll
            for (int j = 0; j < 4; j++) {
                const int col = col0 + ncol0 + j * 16 + m;
                const float bi = bias[col];
#pragma unroll
                for (int r = 0; r < 4; r++)
                    Cb[(size_t)(rbase + r) * ldC + col] = acc[i][j][r] + bi;
            }
        }
    }
}

// ---------------------------------------------------------------------------
// Fused projections: v (448 heavy 128x128 blocks first), then q+k (640
// 128x64 blocks). One launch = better CU fill + one fewer launch gap.
// A operands are the RAW fp32 inputs (cast fused into staging).
// ---------------------------------------------------------------------------
__global__ __launch_bounds__(256)
void proj_kernel(const float* __restrict__ q, const float* __restrict__ k,
                 const float* __restrict__ v,
                 const us* __restrict__ Wqt, const us* __restrict__ Wkt,
                 const us* __restrict__ Wvt,
                 const float* __restrict__ bq, const float* __restrict__ bk,
                 const float* __restrict__ bv,
                 us* __restrict__ qbuf, us* __restrict__ kbuf,
                 us* __restrict__ vbuf)
{
    __shared__ us As[128 * 64];
    __shared__ us Bs[128 * 64];
    const int b = blockIdx.x;
    if (b < 448) {
        const int bx = b & 63, cy = b >> 6;          // 64 x 7
        gemm128_core<true>(v, Wvt, bv, vbuf, D_MODEL, N_CAT, 1,
                           bx << 7, cy << 7, As, Bs);
    } else {
        const int idx = b - 448;
        const int bx = idx & 63;
        const int rest = idx >> 6;                   // 0..9
        const int cy = rest % 5, z = rest / 5;
        gemm64_core<true>(z ? (const void*)k : (const void*)q,
                          z ? Wkt : Wqt, z ? bk : bq,
                          z ? kbuf : qbuf, D_MODEL, NQK,
                          bx << 7, cy << 6, As, Bs);
    }
}

// out gemm: [8192][896] bf16 @ [896][1024] -> fp32
__global__ __launch_bounds__(256)
void gemm_out(const us* __restrict__ ab, const us* __restrict__ Wct,
              const float* __restrict__ bc, float* __restrict__ out)
{
    __shared__ us As[128 * 64];
    __shared__ us Bs[128 * 64];
    gemm128_core<false>(ab, Wct, bc, out, N_CAT, D_MODEL, 0,
                        (int)(blockIdx.x << 7), (int)(blockIdx.y << 7), As, Bs);
}

// ---------------------------------------------------------------------------
// Score kernel (templated slab rows; split by dilation for occupancy).
// Lane = window index j, half = position parity. b128 LDS dot-product reads.
// grid (128, nsub), sbase selects subhead range.
// ---------------------------------------------------------------------------
template<int ROWS>
__global__ __launch_bounds__(256)
void score_kernel(const us* __restrict__ qb, const us* __restrict__ kb,
                  float* __restrict__ scores, int sbase)
{
    __shared__ uu kslab[ROWS * 36];
    __shared__ uu qslab[64 * 32];

    const int tid  = threadIdx.x;
    const int wave = tid >> 6;
    const int lane = tid & 63;
    const int j    = lane & 31;
    const int half = lane >> 5;
    const int s    = sbase + blockIdx.y;
    const int d    = dil_of_sub(s);
    const int ml0  = blockIdx.x * 64;
    const int l0   = ml0 & 4095;
    const int bm   = ml0 - l0;
    const int W    = 64 + 31 * d;

    const uu* kg = (const uu*)kb;
    const uu* qg = (const uu*)qb;

    for (int idx = tid; idx < W * 32; idx += 256) {
        int r = idx >> 5, c = idx & 31;
        int src = l0 - 16 * d + r;
        src = src < 0 ? 0 : (src > 4095 ? 4095 : src);
        kslab[r * 36 + c] = kg[(size_t)(bm + src) * 160 + s * 32 + c];
    }
    for (int idx = tid; idx < 64 * 32; idx += 256) {
        int r = idx >> 5, c = idx & 31;
        qslab[r * 32 + c] = qg[(size_t)(ml0 + r) * 160 + s * 32 + c];
    }
    __syncthreads();

#pragma unroll
    for (int i = 0; i < 8; i++) {
        const int p = wave * 16 + i * 2 + half;
        const uu4* k4 = (const uu4*)&kslab[(p + j * d) * 36];
        const uu4* q4 = (const uu4*)&qslab[p * 32];
        float acc = 0.f;
#pragma unroll
        for (int q = 0; q < 8; q++) {
            uu4 kd = k4[q];
            uu4 qd = q4[q];
            acc = fmaf(blo(kd.x), blo(qd.x), acc); acc = fmaf(bhi(kd.x), bhi(qd.x), acc);
            acc = fmaf(blo(kd.y), blo(qd.y), acc); acc = fmaf(bhi(kd.y), bhi(qd.y), acc);
            acc = fmaf(blo(kd.z), blo(qd.z), acc); acc = fmaf(bhi(kd.z), bhi(qd.z), acc);
            acc = fmaf(blo(kd.w), blo(qd.w), acc); acc = fmaf(bhi(kd.w), bhi(qd.w), acc);
        }
        scores[((size_t)s * M_ROWS + ml0 + p) * 32 + j] = acc * 0.125f;
    }
}

// ---------------------------------------------------------------------------
// Head kernel (templated slab rows; split by dilation).
// vslab stride 36 (16B-aligned, <=2-way banks). sab: scores overlaid by attn
// (rows are wave-private). Phase 1: resample (b128 broadcast) + softmax.
// Phase 2: PV with lane=(position-octet o, channel-chunk c): one b128 per
// (mm,pass) serves 8 positions; attn broadcast banks (4p+mm) distinct per o.
// grid (128, nheads), hbase selects head range.
// ---------------------------------------------------------------------------
template<int ROWS>
__global__ __launch_bounds__(256)
void head_kernel(const float* __restrict__ scores, const us* __restrict__ vb,
                 const float* __restrict__ Ws, const float* __restrict__ bs,
                 us* __restrict__ ab, int hbase)
{
    __shared__ uu    vslab[ROWS * 36];
    __shared__ float sab[64 * 36];

    const int tid  = threadIdx.x;
    const int wave = tid >> 6;
    const int lane = tid & 63;
    const int j    = lane & 31;
    const int half = lane >> 5;
    const int h    = hbase + blockIdx.y;
    const int s    = subhead_of(h);
    const int d    = dil_of_sub(s);
    const int ml0  = blockIdx.x * 64;
    const int l0   = ml0 & 4095;
    const int bm   = ml0 - l0;
    const int W    = 64 + 31 * d;

    const uu* vg = (const uu*)vb;
    for (int idx = tid; idx < W * 32; idx += 256) {
        int r = idx >> 5, c = idx & 31;
        int src = l0 - 16 * d + r;
        src = src < 0 ? 0 : (src > 4095 ? 4095 : src);
        vslab[r * 36 + c] = vg[(size_t)(bm + src) * 448 + h * 32 + c];
    }
    {
        const float4* g4 = (const float4*)(scores + ((size_t)s * M_ROWS + ml0) * 32);
#pragma unroll
        for (int t = 0; t < 2; t++) {
            int i4 = t * 256 + tid;
            int r = i4 >> 3, c4 = i4 & 7;
            *(float4*)&sab[r * 36 + c4 * 4] = g4[i4];
        }
    }
    float wsr[32];
#pragma unroll
    for (int k = 0; k < 32; k++) wsr[k] = Ws[(size_t)h * 1024 + k * 32 + j];
    const float bsv = bs[h * 32 + j];
    __syncthreads();

    // ---- phase 1: resample + softmax; attn overwrites score row in sab ----
#pragma unroll
    for (int i = 0; i < 8; i++) {
        const int p = wave * 16 + i * 2 + half;
        const float4* s4 = (const float4*)&sab[p * 36];
        float acc = bsv;
#pragma unroll
        for (int q = 0; q < 8; q++) {
            float4 v = s4[q];
            acc = fmaf(v.x, wsr[q * 4 + 0], acc);
            acc = fmaf(v.y, wsr[q * 4 + 1], acc);
            acc = fmaf(v.z, wsr[q * 4 + 2], acc);
            acc = fmaf(v.w, wsr[q * 4 + 3], acc);
        }
        float mx = acc;
#pragma unroll
        for (int off = 16; off > 0; off >>= 1) mx = fmaxf(mx, __shfl_xor(mx, off, 64));
        float ex = __expf(acc - mx);
        float sum = ex;
#pragma unroll
        for (int off = 16; off > 0; off >>= 1) sum += __shfl_xor(sum, off, 64);
        sab[p * 36 + j] = ex / sum;
    }

    // ---- phase 2: PV, 8 positions per pass ----
    const int o = lane >> 3;     // position octet
    const int c = lane & 7;      // channel chunk (4 dwords = 8 channels)
#pragma unroll
    for (int pass = 0; pass < 2; pass++) {
        const int p  = wave * 16 + pass * 8 + o;
        const int ml = ml0 + p;
        float a0 = 0.f, a1 = 0.f, a2 = 0.f, a3 = 0.f;
        float a4 = 0.f, a5 = 0.f, a6 = 0.f, a7 = 0.f;
#pragma unroll
        for (int mm = 0; mm < 32; mm++) {
            const float at = sab[p * 36 + mm];
            uu4 vd = *(const uu4*)&vslab[(p + mm * d) * 36 + c * 4];
            a0 = fmaf(blo(vd.x), at, a0); a1 = fmaf(bhi(vd.x), at, a1);
            a2 = fmaf(blo(vd.y), at, a2); a3 = fmaf(bhi(vd.y), at, a3);
            a4 = fmaf(blo(vd.z), at, a4); a5 = fmaf(bhi(vd.z), at, a5);
            a6 = fmaf(blo(vd.w), at, a6); a7 = fmaf(bhi(vd.w), at, a7);
        }
        uu4 od;
        od.x = pack2(a0, a1); od.y = pack2(a2, a3);
        od.z = pack2(a4, a5); od.w = pack2(a6, a7);
        *(uu4*)&((uu*)ab)[(size_t)ml * 448 + h * 32 + c * 4] = od;
    }
}

// ---------------------------------------------------------------------------
extern "C" void kernel_launch(void* const* d_in, const int* in_sizes, int n_in,
                              void* d_out, int out_size, void* d_ws, size_t ws_size,
                              hipStream_t stream)
{
    const float* query = (const float*)d_in[0];
    const float* key   = (const float*)d_in[1];
    const float* value = (const float*)d_in[2];
    const float* Wq    = (const float*)d_in[3];
    const float* bq    = (const float*)d_in[4];
    const float* Wk    = (const float*)d_in[5];
    const float* bk    = (const float*)d_in[6];
    const float* Wv    = (const float*)d_in[7];
    const float* bv    = (const float*)d_in[8];
    const float* Ws    = (const float*)d_in[9];
    const float* bs    = (const float*)d_in[10];
    const float* Wc    = (const float*)d_in[11];
    const float* bc    = (const float*)d_in[12];
    float* out = (float*)d_out;

    // workspace carve (bf16 elements). Same layout as before; the Xq/Xk/Xv
    // cast buffers are now unused (cast fused into proj), but ab and scores
    // keep their aliased slots.
    us* w = (us*)d_ws;
    us* Xq  = w;                          // (unused as cast buf)
    us* ab  = w;                          // 8192*896
    us* Xk  = Xq  + (size_t)M_ROWS * D_MODEL;
    float* scores = (float*)Xk;           // 5*8192*32 f32
    us* Xv  = Xk  + (size_t)M_ROWS * D_MODEL;
    us* Wqt = Xv  + (size_t)M_ROWS * D_MODEL;           // [320][1024]
    us* Wkt = Wqt + (size_t)SUBHEADS * D_INT * D_MODEL;
    us* Wvt = Wkt + (size_t)SUBHEADS * D_INT * D_MODEL; // [896][1024]
    us* Wct = Wvt + (size_t)HEADS * D_INT * D_MODEL;    // [1024][896]
    us* qbuf = Wct + (size_t)D_MODEL * N_CAT;           // [8192][320]
    us* kbuf = qbuf + (size_t)M_ROWS * NQK;
    us* vbuf = kbuf + (size_t)M_ROWS * NQK;             // [8192][896]

    dim3 blk(256);

    // prep: weight transpose-casts only
    prep_kernel<<<dim3(2432), blk, 0, stream>>>(
        Wq, Wk, Wv, Wc, Wqt, Wkt, Wvt, Wct);

    // fused q/k/v projections (fp32 A, cast in staging): 1088 blocks
    proj_kernel<<<dim3(1088), blk, 0, stream>>>(
        query, key, value, Wqt, Wkt, Wvt, bq, bk, bv, qbuf, kbuf, vbuf);

    // scores, split by dilation (subheads 0-2: W<=126; 3-4: W<=312)
    score_kernel<126><<<dim3(M_ROWS / 64, 3), blk, 0, stream>>>(qbuf, kbuf, scores, 0);
    score_kernel<312><<<dim3(M_ROWS / 64, 2), blk, 0, stream>>>(qbuf, kbuf, scores, 3);

    // heads, split by dilation (heads 0-11: d<=2, W<=126; 12-13: W<=312)
    head_kernel<312><<<dim3(M_ROWS / 64, 2),  blk, 0, stream>>>(scores, vbuf, Ws, bs, ab, 12);
    head_kernel<126><<<dim3(M_ROWS / 64, 12), blk, 0, stream>>>(scores, vbuf, Ws, bs, ab, 0);

    // out gemm: [8192][896] @ [896][1024] -> fp32 (128x128 tile)
    gemm_out<<<dim3(M_ROWS / 128, D_MODEL / 128), blk, 0, stream>>>(
        ab, Wct, bc, out);
}

// Round 2
// 286.241 us; speedup vs baseline: 1.0086x; 1.0086x over previous
//
#include <hip/hip_runtime.h>
#include <math.h>

#define D_MODEL 1024
#define D_INT   64
#define KW      32
#define L_SEQ   4096
#define SUBHEADS 5
#define HEADS   14
#define M_ROWS  8192
#define N_CAT   896
#define NQK     320          // SUBHEADS*64

typedef unsigned short us;
typedef unsigned int   uu;
typedef __attribute__((ext_vector_type(4))) unsigned int uu4;
typedef __attribute__((ext_vector_type(8))) short bf16x8_t;
typedef __attribute__((ext_vector_type(4))) float f32x4_t;

__device__ __forceinline__ float u2f(uu u) {
    float f; __builtin_memcpy(&f, &u, 4); return f;
}
__device__ __forceinline__ float blo(uu u) { return u2f(u << 16); }
__device__ __forceinline__ float bhi(uu u) { return u2f(u & 0xffff0000u); }
__device__ __forceinline__ us f2b(float f) {
    uu u; __builtin_memcpy(&u, &f, 4);
    u += 0x7fffu + ((u >> 16) & 1u);
    return (us)(u >> 16);
}
__device__ __forceinline__ uu pack2(float a, float b) {
    return (uu)f2b(a) | ((uu)f2b(b) << 16);
}
// hardware packed cvt: dst = {bf16(a) lo, bf16(b) hi}, RNE — bit-identical to pack2
__device__ __forceinline__ uu cvtpk(float a, float b) {
    uu r;
    asm("v_cvt_pk_bf16_f32 %0, %1, %2" : "=v"(r) : "v"(a), "v"(b));
    return r;
}
__device__ __forceinline__ void load16(void* lds, const void* g) {
    __builtin_amdgcn_global_load_lds(
        (const __attribute__((address_space(1))) unsigned int*)g,
        (__attribute__((address_space(3))) unsigned int*)lds, 16, 0, 0);
}
__device__ __forceinline__ int subhead_of(int h) {
    return (h < 5) ? 0 : (h < 10) ? 1 : (h < 12) ? 2 : (h == 12) ? 3 : 4;
}
__device__ __forceinline__ int dil_of_sub(int s) {
    return (s <= 1) ? 1 : (1 << (s - 1));   // 1,1,2,4,8
}

// ---------------------------------------------------------------------------
// Prep: weight transpose-casts only (Wq,Wk,Wv,Wc).
// grid: 320+320+896+896 = 2432 blocks
// ---------------------------------------------------------------------------
__global__ __launch_bounds__(256)
void prep_kernel(const float* __restrict__ Wq, const float* __restrict__ Wk,
                 const float* __restrict__ Wv, const float* __restrict__ Wc,
                 us* __restrict__ Wqt, us* __restrict__ Wkt,
                 us* __restrict__ Wvt, us* __restrict__ Wct)
{
    __shared__ float t[32][33];
    const int tid = threadIdx.x;
    int g = blockIdx.x;
    const float* S; us* D; int K, N;
    if (g < 640) {
        if (g < 320) { S = Wq; D = Wqt; } else { S = Wk; D = Wkt; g -= 320; }
        K = 1024; N = 64;
    } else if (g < 1536) {
        g -= 640; S = Wv; D = Wvt; K = 1024; N = 64;
    } else {
        g -= 1536; S = Wc; D = Wct; K = 896; N = 1024;
    }
    const int nkx = K >> 5;
    const int kx = g % nkx;
    const int rest = g / nkx;
    const int ny = rest % (N >> 5);
    const int z  = rest / (N >> 5);
    const int k0 = kx * 32, n0 = ny * 32;
    S += (size_t)z * K * N;
    D += (size_t)z * K * N;
    const int tx = tid & 31, ty = tid >> 5;
#pragma unroll
    for (int r = 0; r < 32; r += 8)
        t[r + ty][tx] = S[(size_t)(k0 + r + ty) * N + n0 + tx];
    __syncthreads();
#pragma unroll
    for (int r = 0; r < 32; r += 8)
        D[(size_t)(n0 + r + ty) * K + k0 + tx] = f2b(t[tx][r + ty]);
}

// ---------------------------------------------------------------------------
// shared 128x64-tile GEMM core (BK=64, XOR-swizzled LDS).
// AF32: A fp32 in global, cast fused into staging with a T14 async split:
//   issue A dwordx4 loads at ITERATION TOP (hide HBM latency under MFMA),
//   consume (vmcnt wait -> cvt_pk -> ds_write_b128) AFTER the read-barrier.
// Read-barrier is a raw s_barrier (no vmcnt drain -> A prefetch stays in
// flight); write-barrier is __syncthreads (its drain fences LDS writes).
// ---------------------------------------------------------------------------
template<bool AF32>
__device__ __forceinline__
void gemm64_core(const void* __restrict__ Av, const us* __restrict__ Bt,
                 const float* __restrict__ bias, us* __restrict__ C,
                 int K, int ldC, int row0, int col0, us* As, us* Bs)
{
    const int tid = threadIdx.x, w = tid >> 6, lane = tid & 63;
    const int m = lane & 15, quad = lane >> 4;
    const int sr = lane >> 3;
    const int scs = (lane & 7) ^ sr;

    f32x4_t z4 = {0.f, 0.f, 0.f, 0.f};
    f32x4_t acc[2][4] = {{z4, z4, z4, z4}, {z4, z4, z4, z4}};

    float4 pa[4][2];

    // prologue: stage tile 0
#pragma unroll
    for (int p = 0; p < 2; p++) {
        const int r = w * 16 + p * 8 + sr;
        load16(&Bs[(w * 16 + p * 8) * 64], Bt + (size_t)(col0 + r) * K + scs * 8);
    }
#pragma unroll
    for (int p = 0; p < 4; p++) {
        const int r = w * 32 + p * 8 + sr;
        if constexpr (AF32) {
            const float* ag = (const float*)Av + (size_t)(row0 + r) * K + scs * 8;
            pa[p][0] = *(const float4*)ag;
            pa[p][1] = *(const float4*)(ag + 4);
        } else {
            load16(&As[(w * 32 + p * 8) * 64],
                   (const us*)Av + (size_t)(row0 + r) * K + scs * 8);
        }
    }
    if constexpr (AF32) {
#pragma unroll
        for (int p = 0; p < 4; p++) {
            uu4 o;
            o.x = cvtpk(pa[p][0].x, pa[p][0].y); o.y = cvtpk(pa[p][0].z, pa[p][0].w);
            o.z = cvtpk(pa[p][1].x, pa[p][1].y); o.w = cvtpk(pa[p][1].z, pa[p][1].w);
            *(uu4*)&As[(w * 32 + p * 8 + sr) * 64 + (lane & 7) * 8] = o;
        }
    }
    __syncthreads();

    for (int k0 = 0; k0 < K; k0 += 64) {
        const int kn = k0 + 64;
        if constexpr (AF32) {
            if (kn < K) {
#pragma unroll
                for (int p = 0; p < 4; p++) {
                    const int r = w * 32 + p * 8 + sr;
                    const float* ag = (const float*)Av + (size_t)(row0 + r) * K + kn + scs * 8;
                    pa[p][0] = *(const float4*)ag;
                    pa[p][1] = *(const float4*)(ag + 4);
                }
            }
        }
#pragma unroll
        for (int ks = 0; ks < 2; ks++) {
            const int slot = ((ks * 4 + quad) ^ (m & 7)) * 8;
            bf16x8_t a0 = *(const bf16x8_t*)&As[(w * 32 + m) * 64 + slot];
            bf16x8_t a1 = *(const bf16x8_t*)&As[(w * 32 + 16 + m) * 64 + slot];
#pragma unroll
            for (int t = 0; t < 4; t++) {
                bf16x8_t bb = *(const bf16x8_t*)&Bs[(t * 16 + m) * 64 + slot];
                acc[0][t] = __builtin_amdgcn_mfma_f32_16x16x32_bf16(a0, bb, acc[0][t], 0, 0, 0);
                acc[1][t] = __builtin_amdgcn_mfma_f32_16x16x32_bf16(a1, bb, acc[1][t], 0, 0, 0);
            }
        }
        if (kn < K) {
            __builtin_amdgcn_s_barrier();   // reads done; A prefetch stays in flight
#pragma unroll
            for (int p = 0; p < 2; p++) {
                const int r = w * 16 + p * 8 + sr;
                load16(&Bs[(w * 16 + p * 8) * 64], Bt + (size_t)(col0 + r) * K + kn + scs * 8);
            }
            if constexpr (AF32) {
#pragma unroll
                for (int p = 0; p < 4; p++) {
                    uu4 o;
                    o.x = cvtpk(pa[p][0].x, pa[p][0].y); o.y = cvtpk(pa[p][0].z, pa[p][0].w);
                    o.z = cvtpk(pa[p][1].x, pa[p][1].y); o.w = cvtpk(pa[p][1].z, pa[p][1].w);
                    *(uu4*)&As[(w * 32 + p * 8 + sr) * 64 + (lane & 7) * 8] = o;
                }
            } else {
#pragma unroll
                for (int p = 0; p < 4; p++) {
                    const int r = w * 32 + p * 8 + sr;
                    load16(&As[(w * 32 + p * 8) * 64],
                           (const us*)Av + (size_t)(row0 + r) * K + kn + scs * 8);
                }
            }
            __syncthreads();                // drains vmcnt+lgkm: LDS writes fenced
        }
    }

#pragma unroll
    for (int tm = 0; tm < 2; tm++) {
        const int rbase = row0 + w * 32 + tm * 16 + quad * 4;
#pragma unroll
        for (int t = 0; t < 4; t++) {
            const int col = col0 + t * 16 + m;
            const float bi = bias[col];
#pragma unroll
            for (int r = 0; r < 4; r++)
                C[(size_t)(rbase + r) * ldC + col] = f2b(acc[tm][t][r] + bi);
        }
    }
}

// ---------------------------------------------------------------------------
// 128x128-tile core (m97 structure), same T14 async AF32 staging.
// ---------------------------------------------------------------------------
template<bool AF32>
__device__ __forceinline__
void gemm128_core(const void* __restrict__ Av, const us* __restrict__ Bt,
                  const float* __restrict__ bias, void* __restrict__ Cv,
                  int K, int ldC, int outBf16, int row0, int col0,
                  us* As, us* Bs)
{
    const int tid = threadIdx.x, w = tid >> 6, lane = tid & 63;
    const int m = lane & 15, quad = lane >> 4;
    const int sr = lane >> 3;
    const int scs = (lane & 7) ^ sr;
    const int mrow0 = (w & 1) * 64, ncol0 = (w >> 1) * 64;

    f32x4_t z = {0.f, 0.f, 0.f, 0.f};
    f32x4_t acc[4][4] = {{z,z,z,z},{z,z,z,z},{z,z,z,z},{z,z,z,z}};

    float4 pa[4][2];

    // prologue: stage tile 0
#pragma unroll
    for (int p = 0; p < 4; p++) {
        const int r = w * 32 + p * 8 + sr;
        load16(&Bs[(w * 32 + p * 8) * 64], Bt + (size_t)(col0 + r) * K + scs * 8);
        if constexpr (AF32) {
            const float* ag = (const float*)Av + (size_t)(row0 + r) * K + scs * 8;
            pa[p][0] = *(const float4*)ag;
            pa[p][1] = *(const float4*)(ag + 4);
        } else {
            load16(&As[(w * 32 + p * 8) * 64],
                   (const us*)Av + (size_t)(row0 + r) * K + scs * 8);
        }
    }
    if constexpr (AF32) {
#pragma unroll
        for (int p = 0; p < 4; p++) {
            uu4 o;
            o.x = cvtpk(pa[p][0].x, pa[p][0].y); o.y = cvtpk(pa[p][0].z, pa[p][0].w);
            o.z = cvtpk(pa[p][1].x, pa[p][1].y); o.w = cvtpk(pa[p][1].z, pa[p][1].w);
            *(uu4*)&As[(w * 32 + p * 8 + sr) * 64 + (lane & 7) * 8] = o;
        }
    }
    __syncthreads();

    for (int k0 = 0; k0 < K; k0 += 64) {
        const int kn = k0 + 64;
        if constexpr (AF32) {
            if (kn < K) {
#pragma unroll
                for (int p = 0; p < 4; p++) {
                    const int r = w * 32 + p * 8 + sr;
                    const float* ag = (const float*)Av + (size_t)(row0 + r) * K + kn + scs * 8;
                    pa[p][0] = *(const float4*)ag;
                    pa[p][1] = *(const float4*)(ag + 4);
                }
            }
        }
#pragma unroll
        for (int ks = 0; ks < 2; ks++) {
            const int slot = ((ks * 4 + quad) ^ (m & 7)) * 8;
            bf16x8_t a[4], b[4];
#pragma unroll
            for (int t = 0; t < 4; t++) {
                a[t] = *(const bf16x8_t*)&As[(mrow0 + t * 16 + m) * 64 + slot];
                b[t] = *(const bf16x8_t*)&Bs[(ncol0 + t * 16 + m) * 64 + slot];
            }
#pragma unroll
            for (int i = 0; i < 4; i++)
#pragma unroll
                for (int j = 0; j < 4; j++)
                    acc[i][j] = __builtin_amdgcn_mfma_f32_16x16x32_bf16(a[i], b[j], acc[i][j], 0, 0, 0);
        }
        if (kn < K) {
            __builtin_amdgcn_s_barrier();   // reads done; A prefetch stays in flight
#pragma unroll
            for (int p = 0; p < 4; p++) {
                const int r = w * 32 + p * 8 + sr;
                load16(&Bs[(w * 32 + p * 8) * 64], Bt + (size_t)(col0 + r) * K + kn + scs * 8);
                if constexpr (!AF32) {
                    load16(&As[(w * 32 + p * 8) * 64],
                           (const us*)Av + (size_t)(row0 + r) * K + kn + scs * 8);
                }
            }
            if constexpr (AF32) {
#pragma unroll
                for (int p = 0; p < 4; p++) {
                    uu4 o;
                    o.x = cvtpk(pa[p][0].x, pa[p][0].y); o.y = cvtpk(pa[p][0].z, pa[p][0].w);
                    o.z = cvtpk(pa[p][1].x, pa[p][1].y); o.w = cvtpk(pa[p][1].z, pa[p][1].w);
                    *(uu4*)&As[(w * 32 + p * 8 + sr) * 64 + (lane & 7) * 8] = o;
                }
            }
            __syncthreads();                // drains vmcnt+lgkm: LDS writes fenced
        }
    }

#pragma unroll
    for (int i = 0; i < 4; i++) {
        const int rbase = row0 + mrow0 + i * 16 + quad * 4;
        if (outBf16) {
            us* Cb = (us*)Cv;
#pragma unroll
            for (int j = 0; j < 4; j++) {
                const int col = col0 + ncol0 + j * 16 + m;
                const float bi = bias[col];
#pragma unroll
                for (int r = 0; r < 4; r++)
                    Cb[(size_t)(rbase + r) * ldC + col] = f2b(acc[i][j][r] + bi);
            }
        } else {
            float* Cb = (float*)Cv;
#pragma unroll
            for (int j = 0; j < 4; j++) {
                const int col = col0 + ncol0 + j * 16 + m;
                const float bi = bias[col];
#pragma unroll
                for (int r = 0; r < 4; r++)
                    Cb[(size_t)(rbase + r) * ldC + col] = acc[i][j][r] + bi;
            }
        }
    }
}

// ---------------------------------------------------------------------------
// Fused projections: v (448 heavy 128x128 blocks first), then q+k (640
// 128x64 blocks). A operands are RAW fp32 inputs (cast fused into staging).
// ---------------------------------------------------------------------------
__global__ __launch_bounds__(256)
void proj_kernel(const float* __restrict__ q, const float* __restrict__ k,
                 const float* __restrict__ v,
                 const us* __restrict__ Wqt, const us* __restrict__ Wkt,
                 const us* __restrict__ Wvt,
                 const float* __restrict__ bq, const float* __restrict__ bk,
                 const float* __restrict__ bv,
                 us* __restrict__ qbuf, us* __restrict__ kbuf,
                 us* __restrict__ vbuf)
{
    __shared__ us As[128 * 64];
    __shared__ us Bs[128 * 64];
    const int b = blockIdx.x;
    if (b < 448) {
        const int bx = b & 63, cy = b >> 6;          // 64 x 7
        gemm128_core<true>(v, Wvt, bv, vbuf, D_MODEL, N_CAT, 1,
                           bx << 7, cy << 7, As, Bs);
    } else {
        const int idx = b - 448;
        const int bx = idx & 63;
        const int rest = idx >> 6;                   // 0..9
        const int cy = rest % 5, z = rest / 5;
        gemm64_core<true>(z ? (const void*)k : (const void*)q,
                          z ? Wkt : Wqt, z ? bk : bq,
                          z ? kbuf : qbuf, D_MODEL, NQK,
                          bx << 7, cy << 6, As, Bs);
    }
}

// out gemm: [8192][896] bf16 @ [896][1024] -> fp32
__global__ __launch_bounds__(256)
void gemm_out(const us* __restrict__ ab, const us* __restrict__ Wct,
              const float* __restrict__ bc, float* __restrict__ out)
{
    __shared__ us As[128 * 64];
    __shared__ us Bs[128 * 64];
    gemm128_core<false>(ab, Wct, bc, out, N_CAT, D_MODEL, 0,
                        (int)(blockIdx.x << 7), (int)(blockIdx.y << 7), As, Bs);
}

// ---------------------------------------------------------------------------
// Score kernel (templated slab rows; split by dilation for occupancy).
// ---------------------------------------------------------------------------
template<int ROWS>
__global__ __launch_bounds__(256)
void score_kernel(const us* __restrict__ qb, const us* __restrict__ kb,
                  float* __restrict__ scores, int sbase)
{
    __shared__ uu kslab[ROWS * 36];
    __shared__ uu qslab[64 * 32];

    const int tid  = threadIdx.x;
    const int wave = tid >> 6;
    const int lane = tid & 63;
    const int j    = lane & 31;
    const int half = lane >> 5;
    const int s    = sbase + blockIdx.y;
    const int d    = dil_of_sub(s);
    const int ml0  = blockIdx.x * 64;
    const int l0   = ml0 & 4095;
    const int bm   = ml0 - l0;
    const int W    = 64 + 31 * d;

    const uu* kg = (const uu*)kb;
    const uu* qg = (const uu*)qb;

    for (int idx = tid; idx < W * 32; idx += 256) {
        int r = idx >> 5, c = idx & 31;
        int src = l0 - 16 * d + r;
        src = src < 0 ? 0 : (src > 4095 ? 4095 : src);
        kslab[r * 36 + c] = kg[(size_t)(bm + src) * 160 + s * 32 + c];
    }
    for (int idx = tid; idx < 64 * 32; idx += 256) {
        int r = idx >> 5, c = idx & 31;
        qslab[r * 32 + c] = qg[(size_t)(ml0 + r) * 160 + s * 32 + c];
    }
    __syncthreads();

#pragma unroll
    for (int i = 0; i < 8; i++) {
        const int p = wave * 16 + i * 2 + half;
        const uu4* k4 = (const uu4*)&kslab[(p + j * d) * 36];
        const uu4* q4 = (const uu4*)&qslab[p * 32];
        float acc = 0.f;
#pragma unroll
        for (int q = 0; q < 8; q++) {
            uu4 kd = k4[q];
            uu4 qd = q4[q];
            acc = fmaf(blo(kd.x), blo(qd.x), acc); acc = fmaf(bhi(kd.x), bhi(qd.x), acc);
            acc = fmaf(blo(kd.y), blo(qd.y), acc); acc = fmaf(bhi(kd.y), bhi(qd.y), acc);
            acc = fmaf(blo(kd.z), blo(qd.z), acc); acc = fmaf(bhi(kd.z), bhi(qd.z), acc);
            acc = fmaf(blo(kd.w), blo(qd.w), acc); acc = fmaf(bhi(kd.w), bhi(qd.w), acc);
        }
        scores[((size_t)s * M_ROWS + ml0 + p) * 32 + j] = acc * 0.125f;
    }
}

// ---------------------------------------------------------------------------
// Head kernel (templated slab rows; split by dilation).
// ---------------------------------------------------------------------------
template<int ROWS>
__global__ __launch_bounds__(256)
void head_kernel(const float* __restrict__ scores, const us* __restrict__ vb,
                 const float* __restrict__ Ws, const float* __restrict__ bs,
                 us* __restrict__ ab, int hbase)
{
    __shared__ uu    vslab[ROWS * 36];
    __shared__ float sab[64 * 36];

    const int tid  = threadIdx.x;
    const int wave = tid >> 6;
    const int lane = tid & 63;
    const int j    = lane & 31;
    const int half = lane >> 5;
    const int h    = hbase + blockIdx.y;
    const int s    = subhead_of(h);
    const int d    = dil_of_sub(s);
    const int ml0  = blockIdx.x * 64;
    const int l0   = ml0 & 4095;
    const int bm   = ml0 - l0;
    const int W    = 64 + 31 * d;

    const uu* vg = (const uu*)vb;
    for (int idx = tid; idx < W * 32; idx += 256) {
        int r = idx >> 5, c = idx & 31;
        int src = l0 - 16 * d + r;
        src = src < 0 ? 0 : (src > 4095 ? 4095 : src);
        vslab[r * 36 + c] = vg[(size_t)(bm + src) * 448 + h * 32 + c];
    }
    {
        const float4* g4 = (const float4*)(scores + ((size_t)s * M_ROWS + ml0) * 32);
#pragma unroll
        for (int t = 0; t < 2; t++) {
            int i4 = t * 256 + tid;
            int r = i4 >> 3, c4 = i4 & 7;
            *(float4*)&sab[r * 36 + c4 * 4] = g4[i4];
        }
    }
    float wsr[32];
#pragma unroll
    for (int k = 0; k < 32; k++) wsr[k] = Ws[(size_t)h * 1024 + k * 32 + j];
    const float bsv = bs[h * 32 + j];
    __syncthreads();

    // ---- phase 1: resample + softmax; attn overwrites score row in sab ----
#pragma unroll
    for (int i = 0; i < 8; i++) {
        const int p = wave * 16 + i * 2 + half;
        const float4* s4 = (const float4*)&sab[p * 36];
        float acc = bsv;
#pragma unroll
        for (int q = 0; q < 8; q++) {
            float4 v = s4[q];
            acc = fmaf(v.x, wsr[q * 4 + 0], acc);
            acc = fmaf(v.y, wsr[q * 4 + 1], acc);
            acc = fmaf(v.z, wsr[q * 4 + 2], acc);
            acc = fmaf(v.w, wsr[q * 4 + 3], acc);
        }
        float mx = acc;
#pragma unroll
        for (int off = 16; off > 0; off >>= 1) mx = fmaxf(mx, __shfl_xor(mx, off, 64));
        float ex = __expf(acc - mx);
        float sum = ex;
#pragma unroll
        for (int off = 16; off > 0; off >>= 1) sum += __shfl_xor(sum, off, 64);
        sab[p * 36 + j] = ex / sum;
    }

    // ---- phase 2: PV, 8 positions per pass ----
    const int o = lane >> 3;     // position octet
    const int c = lane & 7;      // channel chunk (4 dwords = 8 channels)
#pragma unroll
    for (int pass = 0; pass < 2; pass++) {
        const int p  = wave * 16 + pass * 8 + o;
        const int ml = ml0 + p;
        float a0 = 0.f, a1 = 0.f, a2 = 0.f, a3 = 0.f;
        float a4 = 0.f, a5 = 0.f, a6 = 0.f, a7 = 0.f;
#pragma unroll
        for (int mm = 0; mm < 32; mm++) {
            const float at = sab[p * 36 + mm];
            uu4 vd = *(const uu4*)&vslab[(p + mm * d) * 36 + c * 4];
            a0 = fmaf(blo(vd.x), at, a0); a1 = fmaf(bhi(vd.x), at, a1);
            a2 = fmaf(blo(vd.y), at, a2); a3 = fmaf(bhi(vd.y), at, a3);
            a4 = fmaf(blo(vd.z), at, a4); a5 = fmaf(bhi(vd.z), at, a5);
            a6 = fmaf(blo(vd.w), at, a6); a7 = fmaf(bhi(vd.w), at, a7);
        }
        uu4 od;
        od.x = pack2(a0, a1); od.y = pack2(a2, a3);
        od.z = pack2(a4, a5); od.w = pack2(a6, a7);
        *(uu4*)&((uu*)ab)[(size_t)ml * 448 + h * 32 + c * 4] = od;
    }
}

// ---------------------------------------------------------------------------
extern "C" void kernel_launch(void* const* d_in, const int* in_sizes, int n_in,
                              void* d_out, int out_size, void* d_ws, size_t ws_size,
                              hipStream_t stream)
{
    const float* query = (const float*)d_in[0];
    const float* key   = (const float*)d_in[1];
    const float* value = (const float*)d_in[2];
    const float* Wq    = (const float*)d_in[3];
    const float* bq    = (const float*)d_in[4];
    const float* Wk    = (const float*)d_in[5];
    const float* bk    = (const float*)d_in[6];
    const float* Wv    = (const float*)d_in[7];
    const float* bv    = (const float*)d_in[8];
    const float* Ws    = (const float*)d_in[9];
    const float* bs    = (const float*)d_in[10];
    const float* Wc    = (const float*)d_in[11];
    const float* bc    = (const float*)d_in[12];
    float* out = (float*)d_out;

    // workspace carve (bf16 elements). ab and scores keep aliased slots.
    us* w = (us*)d_ws;
    us* Xq  = w;                          // (unused as cast buf)
    us* ab  = w;                          // 8192*896
    us* Xk  = Xq  + (size_t)M_ROWS * D_MODEL;
    float* scores = (float*)Xk;           // 5*8192*32 f32
    us* Xv  = Xk  + (size_t)M_ROWS * D_MODEL;
    us* Wqt = Xv  + (size_t)M_ROWS * D_MODEL;           // [320][1024]
    us* Wkt = Wqt + (size_t)SUBHEADS * D_INT * D_MODEL;
    us* Wvt = Wkt + (size_t)SUBHEADS * D_INT * D_MODEL; // [896][1024]
    us* Wct = Wvt + (size_t)HEADS * D_INT * D_MODEL;    // [1024][896]
    us* qbuf = Wct + (size_t)D_MODEL * N_CAT;           // [8192][320]
    us* kbuf = qbuf + (size_t)M_ROWS * NQK;
    us* vbuf = kbuf + (size_t)M_ROWS * NQK;             // [8192][896]

    dim3 blk(256);

    // prep: weight transpose-casts only
    prep_kernel<<<dim3(2432), blk, 0, stream>>>(
        Wq, Wk, Wv, Wc, Wqt, Wkt, Wvt, Wct);

    // fused q/k/v projections (fp32 A, cast in staging): 1088 blocks
    proj_kernel<<<dim3(1088), blk, 0, stream>>>(
        query, key, value, Wqt, Wkt, Wvt, bq, bk, bv, qbuf, kbuf, vbuf);

    // scores, split by dilation (subheads 0-2: W<=126; 3-4: W<=312)
    score_kernel<126><<<dim3(M_ROWS / 64, 3), blk, 0, stream>>>(qbuf, kbuf, scores, 0);
    score_kernel<312><<<dim3(M_ROWS / 64, 2), blk, 0, stream>>>(qbuf, kbuf, scores, 3);

    // heads, split by dilation (heads 0-11: d<=2, W<=126; 12-13: W<=312)
    head_kernel<312><<<dim3(M_ROWS / 64, 2),  blk, 0, stream>>>(scores, vbuf, Ws, bs, ab, 12);
    head_kernel<126><<<dim3(M_ROWS / 64, 12), blk, 0, stream>>>(scores, vbuf, Ws, bs, ab, 0);

    // out gemm: [8192][896] @ [896][1024] -> fp32 (128x128 tile)
    gemm_out<<<dim3(M_ROWS / 128, D_MODEL / 128), blk, 0, stream>>>(
        ab, Wct, bc, out);
}